// Round 7
// baseline (1227.907 us; speedup 1.0000x reference)
//
#include <hip/hip_runtime.h>
#include <hip/hip_bf16.h>
#include <stdint.h>

#define M_TOTAL 8192
#define K_TOTAL 4096
#define N_TOTAL 16384
#define BM 256
#define BN 256
#define BK 32
#define KT2 (K_TOTAL / BK)             // 128 K-tiles of 32
#define TILE_B 16384                   // packed bytes per 256-row block per K-tile (per operand)
#define BUF_S 32768                    // LDS buffer: A 16KB + B 16KB
#define NBUF 4

typedef __bf16 bf16x8 __attribute__((ext_vector_type(8)));
typedef float f32x4 __attribute__((ext_vector_type(4)));
typedef unsigned short u16;
typedef u16 u16x8 __attribute__((ext_vector_type(8)));

static __device__ __forceinline__ u16 f2bf(float f) {
    unsigned int u = __builtin_bit_cast(unsigned int, f);
    u = (u + 0x7fffu + ((u >> 16) & 1u)) >> 16;   // RNE
    return (u16)u;
}

static __device__ __forceinline__ void async16(const void* g, void* l) {
    __builtin_amdgcn_global_load_lds((const __attribute__((address_space(1))) unsigned int*)g,
                                     (__attribute__((address_space(3))) unsigned int*)l,
                                     16, 0, 0);
}

// ---------------- packing kernels ----------------
// Packed layout per 256-row block (2MB): [kt 0..127][f 0..15][lane 0..63][16B]
// element (row, k): f=(row>>4)&15, lane=(row&15)|(((k>>3)&3)<<4), byte=(k&7)*2.
// Frag ds_read = uniform base + lane*16: stride-1, conflict-free, zero VALU.

__global__ __launch_bounds__(256) void cvt_x_pack(const float* __restrict__ x, u16* __restrict__ xb) {
    long long j = (long long)blockIdx.x * 256 + threadIdx.x;
    int mt = (int)(j >> 17);           // 131072 threads per 256-row block
    int j2 = (int)(j & 131071);
    int kt = j2 >> 10;
    int f  = (j2 >> 6) & 15;
    int l  = j2 & 63;
    int r  = mt * 256 + f * 16 + (l & 15);
    int k0 = kt * 32 + ((l >> 4) << 3);
    const float4* s = reinterpret_cast<const float4*>(x + (size_t)r * K_TOTAL + k0);
    float4 a = s[0], b = s[1];
    u16x8 v;
    v[0] = f2bf(a.x); v[1] = f2bf(a.y); v[2] = f2bf(a.z); v[3] = f2bf(a.w);
    v[4] = f2bf(b.x); v[5] = f2bf(b.y); v[6] = f2bf(b.z); v[7] = f2bf(b.w);
    *reinterpret_cast<u16x8*>(xb + j * 8) = v;
}

__global__ __launch_bounds__(256) void cvt_w_pack(const int* __restrict__ w, u16* __restrict__ wb) {
    long long j = (long long)blockIdx.x * 256 + threadIdx.x;
    int nt = (int)(j >> 17);
    int j2 = (int)(j & 131071);
    int kt = j2 >> 10;
    int f  = (j2 >> 6) & 15;
    int l  = j2 & 63;
    int r  = nt * 256 + f * 16 + (l & 15);
    int k0 = kt * 32 + ((l >> 4) << 3);
    const int4* s = reinterpret_cast<const int4*>(w + (size_t)r * K_TOTAL + k0);
    int4 a = s[0], b = s[1];
    u16x8 v;
    v[0] = f2bf((float)a.x); v[1] = f2bf((float)a.y); v[2] = f2bf((float)a.z); v[3] = f2bf((float)a.w);
    v[4] = f2bf((float)b.x); v[5] = f2bf((float)b.y); v[6] = f2bf((float)b.z); v[7] = f2bf((float)b.w);
    *reinterpret_cast<u16x8*>(wb + j * 8) = v;
}

// ---------------- GEMM: MFMA-then-read-next pipelined windows ----------------
// Window t: STG(t+3) ; 32 MFMA on tile t (regs loaded in window t-1) ;
//           12 ds_reads of tile t+1 into the SAME regs ; lgkm0 ; vmcnt(4) ; bar
// The WAR dep (MFMA reads afr/bfr before ds_read overwrites) pins program
// order; LDS pipe services the reads while the matrix pipe drains the MFMA
// queue -> the two 1.2k-cycle pipe floors overlap instead of serializing.
// Buffer safety: tile t+1 published by vmcnt(4)+bar at end of t-1; reads of
// buf retire (lgkm0) 2 barriers before that buf is re-staged.

#define BAR()    { asm volatile("" ::: "memory"); __builtin_amdgcn_s_barrier(); asm volatile("" ::: "memory"); }
#define LGKM0()  asm volatile("s_waitcnt lgkmcnt(0)" ::: "memory")
#define VMC4()   asm volatile("s_waitcnt vmcnt(4)" ::: "memory")
#define VMC0()   asm volatile("s_waitcnt vmcnt(0)" ::: "memory")
#define PRIO1()  __builtin_amdgcn_s_setprio(1)
#define PRIO0()  __builtin_amdgcn_s_setprio(0)

#define STG(ts, so) { \
    async16(aS + (size_t)(ts)*TILE_B + tid*16,        ldsc + (so) + tid*16); \
    async16(aS + (size_t)(ts)*TILE_B + 8192 + tid*16, ldsc + (so) + 8192 + tid*16); \
    async16(bS + (size_t)(ts)*TILE_B + tid*16,        ldsc + (so) + 16384 + tid*16); \
    async16(bS + (size_t)(ts)*TILE_B + 8192 + tid*16, ldsc + (so) + 24576 + tid*16); }

#define RD_FRAGS(bo) { \
    _Pragma("unroll") \
    for (int ni = 0; ni < 4; ++ni) bfr[ni] = *(const bf16x8*)(bRd + (bo) + ni * 1024); \
    _Pragma("unroll") \
    for (int mi = 0; mi < 8; ++mi) afr[mi] = *(const bf16x8*)(aRd + (bo) + mi * 1024); }

#define MMA_ALL() { PRIO1(); \
    _Pragma("unroll") \
    for (int mi = 0; mi < 8; ++mi) { _Pragma("unroll") \
        for (int ni = 0; ni < 4; ++ni) \
            acc[mi][ni] = __builtin_amdgcn_mfma_f32_16x16x32_bf16(afr[mi], bfr[ni], acc[mi][ni], 0, 0, 0); } \
    PRIO0(); }

__global__ __launch_bounds__(512, 2) void gemm_kernel(const u16* __restrict__ A,
                                                      const u16* __restrict__ B,
                                                      const float* __restrict__ scale,
                                                      float* __restrict__ out) {
    extern __shared__ char ldsc[];
    const int tid  = threadIdx.x;
    const int lane = tid & 63;
    const int wave = tid >> 6;
    const int wm = wave >> 2;          // 0..1
    const int wn = wave & 3;           // 0..3

    // XCD-aware bijective swizzle (2048 blocks, 8 XCDs, 256-block chunks);
    // mt fastest within chunk -> 32 co-resident blocks/XCD share one B-panel.
    int orig = blockIdx.x;
    int swzid = (orig & 7) * 256 + (orig >> 3);
    int mt = swzid & 31;
    int nt = swzid >> 5;

    const char* aS = (const char*)A + (size_t)mt * (KT2 * TILE_B);
    const char* bS = (const char*)B + (size_t)nt * (KT2 * TILE_B);

    // fragment read bases: stride-1 1KB wave reads (uniform base + lane*16)
    const char* aRd = ldsc + wm * 8192 + lane * 16;           // + bo + mi*1024
    const char* bRd = ldsc + 16384 + wn * 4096 + lane * 16;   // + bo + ni*1024

    f32x4 acc[8][4];
    #pragma unroll
    for (int mi = 0; mi < 8; ++mi)
        #pragma unroll
        for (int ni = 0; ni < 4; ++ni)
            acc[mi][ni] = (f32x4){0.f, 0.f, 0.f, 0.f};

    bf16x8 afr[8], bfr[4];

    // prologue: stage tiles 0,1,2; certify 0,1; pre-read tile 0 into regs
    STG(0, 0); STG(1, BUF_S); STG(2, 2 * BUF_S);
    VMC4();
    BAR();
    RD_FRAGS(0);

    // windows 0..124: uniform (stages 3..127)
    for (int t = 0; t < 125; ++t) {
        STG(t + 3, ((t + 3) & 3) * BUF_S);
        MMA_ALL();                          // tile t
        RD_FRAGS(((t + 1) & 3) * BUF_S);    // tile t+1 (WAR-ordered after MFMA)
        LGKM0();
        VMC4();                             // certify tile t+2 for next window
        BAR();
    }
    // window 125: certify tile 127 (last stage) with vmcnt(0)
    MMA_ALL();                              // tile 125
    RD_FRAGS(2 * BUF_S);                    // tile 126
    LGKM0();
    VMC0();
    BAR();
    // window 126: no more stages
    MMA_ALL();                              // tile 126
    RD_FRAGS(3 * BUF_S);                    // tile 127
    LGKM0();
    // window 127
    MMA_ALL();                              // tile 127

    // epilogue: D row=(lane>>4)*4+j, col=lane&15; scale per output col
    int m0 = mt * BM, n0 = nt * BN;
    int col0 = n0 + wn * 64 + (lane & 15);
    int row0 = m0 + wm * 128 + ((lane >> 4) << 2);
    #pragma unroll
    for (int ni = 0; ni < 4; ++ni) {
        float sc = scale[col0 + ni * 16];
        #pragma unroll
        for (int mi = 0; mi < 8; ++mi) {
            #pragma unroll
            for (int j = 0; j < 4; ++j) {
                out[(size_t)(row0 + mi * 16 + j) * N_TOTAL + (col0 + ni * 16)] = acc[mi][ni][j] * sc;
            }
        }
    }
}

// ---------------- fallback ----------------

__global__ __launch_bounds__(256) void naive_kernel(const float* __restrict__ x, const int* __restrict__ w,
                                                    const float* __restrict__ scale, float* __restrict__ out) {
    int n = blockIdx.x * 256 + threadIdx.x;
    int m = blockIdx.y;
    const float* xr = x + (size_t)m * K_TOTAL;
    const int*   wr = w + (size_t)n * K_TOTAL;
    float acc = 0.f;
    for (int k = 0; k < K_TOTAL; k += 4) {
        float4 xv = *(const float4*)(xr + k);
        int4   wv = *(const int4*)(wr + k);
        acc += xv.x * (float)wv.x + xv.y * (float)wv.y + xv.z * (float)wv.z + xv.w * (float)wv.w;
    }
    out[(size_t)m * N_TOTAL + n] = acc * scale[n];
}

extern "C" void kernel_launch(void* const* d_in, const int* in_sizes, int n_in,
                              void* d_out, int out_size, void* d_ws, size_t ws_size,
                              hipStream_t stream) {
    const float* x     = (const float*)d_in[0];
    const int*   w     = (const int*)d_in[1];
    const float* scale = (const float*)d_in[2];
    float* out = (float*)d_out;

    const size_t xb_bytes = (size_t)M_TOTAL * K_TOTAL * 2;
    const size_t wb_bytes = (size_t)N_TOTAL * K_TOTAL * 2;

    if (ws_size >= xb_bytes + wb_bytes) {
        u16* xb = (u16*)d_ws;
        u16* wb = (u16*)((char*)d_ws + xb_bytes);
        (void)hipFuncSetAttribute((const void*)gemm_kernel,
                                  hipFuncAttributeMaxDynamicSharedMemorySize, NBUF * BUF_S);
        cvt_x_pack<<<(M_TOTAL / 256) * (K_TOTAL / 8), 256, 0, stream>>>(x, xb);
        cvt_w_pack<<<(N_TOTAL / 256) * (K_TOTAL / 8), 256, 0, stream>>>(w, wb);
        gemm_kernel<<<(M_TOTAL / BM) * (N_TOTAL / BN), 512, NBUF * BUF_S, stream>>>(xb, wb, scale, out);
    } else {
        dim3 g(N_TOTAL / 256, M_TOTAL);
        naive_kernel<<<g, 256, 0, stream>>>(x, w, scale, out);
    }
}

// Round 9
// 1160.078 us; speedup vs baseline: 1.0585x; 1.0585x over previous
//
#include <hip/hip_runtime.h>
#include <hip/hip_bf16.h>
#include <stdint.h>

#define M_TOTAL 8192
#define K_TOTAL 4096
#define N_TOTAL 16384
#define BM 256
#define BN 256
#define BK 32
#define KT2 (K_TOTAL / BK)             // 128 K-tiles of 32
#define TILE_B 16384                   // packed bytes per 256-row block per K-tile (per operand)
#define BUF_S 32768                    // LDS buffer: A 16KB + B 16KB
#define NBUF 4

typedef __bf16 bf16x8 __attribute__((ext_vector_type(8)));
typedef float f32x4 __attribute__((ext_vector_type(4)));
typedef unsigned short u16;
typedef u16 u16x8 __attribute__((ext_vector_type(8)));

static __device__ __forceinline__ u16 f2bf(float f) {
    unsigned int u = __builtin_bit_cast(unsigned int, f);
    u = (u + 0x7fffu + ((u >> 16) & 1u)) >> 16;   // RNE
    return (u16)u;
}

static __device__ __forceinline__ void async16(const void* g, void* l) {
    __builtin_amdgcn_global_load_lds((const __attribute__((address_space(1))) unsigned int*)g,
                                     (__attribute__((address_space(3))) unsigned int*)l,
                                     16, 0, 0);
}

// ---------------- packing kernels ----------------
// Packed layout per 256-row block (2MB): [kt 0..127][f 0..15][lane 0..63][16B]
// element (row, k): f=(row>>4)&15, lane=(row&15)|(((k>>3)&3)<<4), byte=(k&7)*2.
// Frag ds_read = uniform base + lane*16: stride-1, conflict-free, zero VALU.

__global__ __launch_bounds__(256) void cvt_x_pack(const float* __restrict__ x, u16* __restrict__ xb) {
    long long j = (long long)blockIdx.x * 256 + threadIdx.x;
    int mt = (int)(j >> 17);           // 131072 threads per 256-row block
    int j2 = (int)(j & 131071);
    int kt = j2 >> 10;
    int f  = (j2 >> 6) & 15;
    int l  = j2 & 63;
    int r  = mt * 256 + f * 16 + (l & 15);
    int k0 = kt * 32 + ((l >> 4) << 3);
    const float4* s = reinterpret_cast<const float4*>(x + (size_t)r * K_TOTAL + k0);
    float4 a = s[0], b = s[1];
    u16x8 v;
    v[0] = f2bf(a.x); v[1] = f2bf(a.y); v[2] = f2bf(a.z); v[3] = f2bf(a.w);
    v[4] = f2bf(b.x); v[5] = f2bf(b.y); v[6] = f2bf(b.z); v[7] = f2bf(b.w);
    *reinterpret_cast<u16x8*>(xb + j * 8) = v;
}

__global__ __launch_bounds__(256) void cvt_w_pack(const int* __restrict__ w, u16* __restrict__ wb) {
    long long j = (long long)blockIdx.x * 256 + threadIdx.x;
    int nt = (int)(j >> 17);
    int j2 = (int)(j & 131071);
    int kt = j2 >> 10;
    int f  = (j2 >> 6) & 15;
    int l  = j2 & 63;
    int r  = nt * 256 + f * 16 + (l & 15);
    int k0 = kt * 32 + ((l >> 4) << 3);
    const int4* s = reinterpret_cast<const int4*>(w + (size_t)r * K_TOTAL + k0);
    int4 a = s[0], b = s[1];
    u16x8 v;
    v[0] = f2bf((float)a.x); v[1] = f2bf((float)a.y); v[2] = f2bf((float)a.z); v[3] = f2bf((float)a.w);
    v[4] = f2bf((float)b.x); v[5] = f2bf((float)b.y); v[6] = f2bf((float)b.z); v[7] = f2bf((float)b.w);
    *reinterpret_cast<u16x8*>(wb + j * 8) = v;
}

// ---------------- GEMM: register-double-buffered, reads-first windows ----------------
// Window t (phase p = t&3):  STG(t+3) ; 12 ds_reads of tile t+1 -> frag set ~s
// (independent of everything in flight, issue fast, LDS pipe starts serving);
// 32 MFMA on frag set s (operands loaded in window t-1) overlap on the matrix
// pipe; lgkm0 ; vmcnt(4) ; barrier.  sched_barrier pins reads before MFMAs
// (in-order issue means MFMA-first would clog issue behind matrix backpressure).
// Safety: tile t+1 landed by window t-1's vmcnt(4)+bar; staged buffer's last
// reader retired (lgkm0) two barriers before its re-stage. Unroll x4 makes all
// LDS offsets compile-time immediates.

#define BAR()    { asm volatile("" ::: "memory"); __builtin_amdgcn_s_barrier(); asm volatile("" ::: "memory"); }
#define LGKM0()  asm volatile("s_waitcnt lgkmcnt(0)" ::: "memory")
#define VMC4()   asm volatile("s_waitcnt vmcnt(4)" ::: "memory")
#define VMC0()   asm volatile("s_waitcnt vmcnt(0)" ::: "memory")
#define PRIO1()  __builtin_amdgcn_s_setprio(1)
#define PRIO0()  __builtin_amdgcn_s_setprio(0)
#define SCHEDB() __builtin_amdgcn_sched_barrier(0)

#define STG(ts, so) { \
    async16(aS + (size_t)(ts)*TILE_B + tid*16,        ldsc + (so) + tid*16); \
    async16(aS + (size_t)(ts)*TILE_B + 8192 + tid*16, ldsc + (so) + 8192 + tid*16); \
    async16(bS + (size_t)(ts)*TILE_B + tid*16,        ldsc + (so) + 16384 + tid*16); \
    async16(bS + (size_t)(ts)*TILE_B + 8192 + tid*16, ldsc + (so) + 24576 + tid*16); }

#define RDF0(bo) { \
    _Pragma("unroll") for (int ni = 0; ni < 4; ++ni) bfr0[ni] = *(const bf16x8*)(bRd + (bo) + ni * 1024); \
    _Pragma("unroll") for (int mi = 0; mi < 8; ++mi) afr0[mi] = *(const bf16x8*)(aRd + (bo) + mi * 1024); }

#define RDF1(bo) { \
    _Pragma("unroll") for (int ni = 0; ni < 4; ++ni) bfr1[ni] = *(const bf16x8*)(bRd + (bo) + ni * 1024); \
    _Pragma("unroll") for (int mi = 0; mi < 8; ++mi) afr1[mi] = *(const bf16x8*)(aRd + (bo) + mi * 1024); }

#define MMA0() { PRIO1(); \
    _Pragma("unroll") for (int mi = 0; mi < 8; ++mi) { _Pragma("unroll") \
        for (int ni = 0; ni < 4; ++ni) \
            acc[mi][ni] = __builtin_amdgcn_mfma_f32_16x16x32_bf16(afr0[mi], bfr0[ni], acc[mi][ni], 0, 0, 0); } \
    PRIO0(); }

#define MMA1() { PRIO1(); \
    _Pragma("unroll") for (int mi = 0; mi < 8; ++mi) { _Pragma("unroll") \
        for (int ni = 0; ni < 4; ++ni) \
            acc[mi][ni] = __builtin_amdgcn_mfma_f32_16x16x32_bf16(afr1[mi], bfr1[ni], acc[mi][ni], 0, 0, 0); } \
    PRIO0(); }

__global__ __launch_bounds__(512, 2) void gemm_kernel(const u16* __restrict__ A,
                                                      const u16* __restrict__ B,
                                                      const float* __restrict__ scale,
                                                      float* __restrict__ out) {
    extern __shared__ char ldsc[];
    const int tid  = threadIdx.x;
    const int lane = tid & 63;
    const int wave = tid >> 6;
    const int wm = wave >> 2;          // 0..1
    const int wn = wave & 3;           // 0..3

    // XCD-aware bijective swizzle (2048 blocks, 8 XCDs, 256-block chunks);
    // mt fastest within chunk -> 32 co-resident blocks/XCD share one B-panel.
    int orig = blockIdx.x;
    int swzid = (orig & 7) * 256 + (orig >> 3);
    int mt = swzid & 31;
    int nt = swzid >> 5;

    const char* aS = (const char*)A + (size_t)mt * (KT2 * TILE_B);
    const char* bS = (const char*)B + (size_t)nt * (KT2 * TILE_B);

    // fragment read bases: stride-1 1KB wave reads (uniform base + lane*16)
    const char* aRd = ldsc + wm * 8192 + lane * 16;           // + bo + mi*1024
    const char* bRd = ldsc + 16384 + wn * 4096 + lane * 16;   // + bo + ni*1024

    f32x4 acc[8][4];
    #pragma unroll
    for (int mi = 0; mi < 8; ++mi)
        #pragma unroll
        for (int ni = 0; ni < 4; ++ni)
            acc[mi][ni] = (f32x4){0.f, 0.f, 0.f, 0.f};

    bf16x8 afr0[8], bfr0[4], afr1[8], bfr1[4];

    // prologue: stage tiles 0,1,2 -> bufs 0,1,2; certify tiles 0,1; read tile0
    STG(0, 0); STG(1, BUF_S); STG(2, 2 * BUF_S);
    VMC4();
    BAR();
    RDF0(0);
    LGKM0();

    // windows 0..123 (stages 3..126), unroll x4 for static LDS offsets
    for (int t = 0; t < 124; t += 4) {
        // w=t (phase 0): MMA set0 (tile t), read tile t+1 -> set1 (buf1)
        STG(t + 3, 3 * BUF_S);
        RDF1(1 * BUF_S);
        SCHEDB();
        MMA0();
        SCHEDB();
        LGKM0(); VMC4(); BAR();
        // w=t+1: MMA set1, read tile t+2 -> set0 (buf2), stage t+4 -> buf0
        STG(t + 4, 0);
        RDF0(2 * BUF_S);
        SCHEDB();
        MMA1();
        SCHEDB();
        LGKM0(); VMC4(); BAR();
        // w=t+2: MMA set0, read tile t+3 -> set1 (buf3), stage t+5 -> buf1
        STG(t + 5, 1 * BUF_S);
        RDF1(3 * BUF_S);
        SCHEDB();
        MMA0();
        SCHEDB();
        LGKM0(); VMC4(); BAR();
        // w=t+3: MMA set1, read tile t+4 -> set0 (buf0), stage t+6 -> buf2
        STG(t + 6, 2 * BUF_S);
        RDF0(0);
        SCHEDB();
        MMA1();
        SCHEDB();
        LGKM0(); VMC4(); BAR();
    }
    // window 124 (phase 0): stage 127 -> buf3, read tile 125 -> set1 (buf1)
    STG(127, 3 * BUF_S);
    RDF1(1 * BUF_S);
    SCHEDB();
    MMA0();                 // tile 124
    SCHEDB();
    LGKM0(); VMC4(); BAR();
    // window 125: read tile 126 -> set0 (buf2)
    RDF0(2 * BUF_S);
    SCHEDB();
    MMA1();                 // tile 125
    SCHEDB();
    LGKM0(); VMC0(); BAR();
    // window 126: read tile 127 -> set1 (buf3)
    RDF1(3 * BUF_S);
    SCHEDB();
    MMA0();                 // tile 126
    SCHEDB();
    LGKM0();
    // window 127
    MMA1();                 // tile 127

    // epilogue: D row=(lane>>4)*4+j, col=lane&15; scale per output col
    int m0 = mt * BM, n0 = nt * BN;
    int col0 = n0 + wn * 64 + (lane & 15);
    int row0 = m0 + wm * 128 + ((lane >> 4) << 2);
    #pragma unroll
    for (int ni = 0; ni < 4; ++ni) {
        float sc = scale[col0 + ni * 16];
        #pragma unroll
        for (int mi = 0; mi < 8; ++mi) {
            #pragma unroll
            for (int j = 0; j < 4; ++j) {
                out[(size_t)(row0 + mi * 16 + j) * N_TOTAL + (col0 + ni * 16)] = acc[mi][ni][j] * sc;
            }
        }
    }
}

// ---------------- fallback ----------------

__global__ __launch_bounds__(256) void naive_kernel(const float* __restrict__ x, const int* __restrict__ w,
                                                    const float* __restrict__ scale, float* __restrict__ out) {
    int n = blockIdx.x * 256 + threadIdx.x;
    int m = blockIdx.y;
    const float* xr = x + (size_t)m * K_TOTAL;
    const int*   wr = w + (size_t)n * K_TOTAL;
    float acc = 0.f;
    for (int k = 0; k < K_TOTAL; k += 4) {
        float4 xv = *(const float4*)(xr + k);
        int4   wv = *(const int4*)(wr + k);
        acc += xv.x * (float)wv.x + xv.y * (float)wv.y + xv.z * (float)wv.z + xv.w * (float)wv.w;
    }
    out[(size_t)m * N_TOTAL + n] = acc * scale[n];
}

extern "C" void kernel_launch(void* const* d_in, const int* in_sizes, int n_in,
                              void* d_out, int out_size, void* d_ws, size_t ws_size,
                              hipStream_t stream) {
    const float* x     = (const float*)d_in[0];
    const int*   w     = (const int*)d_in[1];
    const float* scale = (const float*)d_in[2];
    float* out = (float*)d_out;

    const size_t xb_bytes = (size_t)M_TOTAL * K_TOTAL * 2;
    const size_t wb_bytes = (size_t)N_TOTAL * K_TOTAL * 2;

    if (ws_size >= xb_bytes + wb_bytes) {
        u16* xb = (u16*)d_ws;
        u16* wb = (u16*)((char*)d_ws + xb_bytes);
        (void)hipFuncSetAttribute((const void*)gemm_kernel,
                                  hipFuncAttributeMaxDynamicSharedMemorySize, NBUF * BUF_S);
        cvt_x_pack<<<(M_TOTAL / 256) * (K_TOTAL / 8), 256, 0, stream>>>(x, xb);
        cvt_w_pack<<<(N_TOTAL / 256) * (K_TOTAL / 8), 256, 0, stream>>>(w, wb);
        gemm_kernel<<<(M_TOTAL / BM) * (N_TOTAL / BN), 512, NBUF * BUF_S, stream>>>(xb, wb, scale, out);
    } else {
        dim3 g(N_TOTAL / 256, M_TOTAL);
        naive_kernel<<<g, 256, 0, stream>>>(x, w, scale, out);
    }
}